// Round 1
// baseline (1362.458 us; speedup 1.0000x reference)
//
#include <hip/hip_runtime.h>
#include <hip/hip_bf16.h>

// PixelArt: out[h][w][:] = palette[argmax_k img_cls[h][w][k]]
// (forward value of straight-through estimator == hard one-hot; softmax is
//  monotone so argmax(softmax(x)) == argmax(x); hard @ palette == row gather)
//
// img_cls: [1024,1024,256] f32 (1 GiB read, HBM-bound), palette: [256,3] f32.
// One wave per pixel: lane i loads float4 at k=i*4 (64 lanes * 16B = the
// pixel's contiguous 1KB), local argmax of 4, 6-step shfl_xor butterfly
// argmax (lowest-index tie-break = jnp.argmax semantics), lanes 0..2 store.

__global__ __launch_bounds__(256) void pixelart_argmax_kernel(
    const float* __restrict__ img,   // [npix, 256]
    const float* __restrict__ pal,   // [256, 3]
    float* __restrict__ out,         // [npix, 3]
    int npix)
{
    const int tid   = blockIdx.x * blockDim.x + threadIdx.x;
    const int wave  = tid >> 6;
    const int lane  = threadIdx.x & 63;
    const int nwave = (gridDim.x * blockDim.x) >> 6;

    for (int p = wave; p < npix; p += nwave) {
        const float4 v =
            reinterpret_cast<const float4*>(img + (size_t)p * 256)[lane];

        float best = v.x;
        int   bidx = lane * 4;
        if (v.y > best) { best = v.y; bidx = lane * 4 + 1; }
        if (v.z > best) { best = v.z; bidx = lane * 4 + 2; }
        if (v.w > best) { best = v.w; bidx = lane * 4 + 3; }

        // 64-lane butterfly argmax; tie -> lower class index (first occurrence)
        #pragma unroll
        for (int off = 32; off >= 1; off >>= 1) {
            float ov = __shfl_xor(best, off, 64);
            int   oi = __shfl_xor(bidx, off, 64);
            if (ov > best || (ov == best && oi < bidx)) {
                best = ov;
                bidx = oi;
            }
        }

        if (lane < 3) {
            out[(size_t)p * 3 + lane] = pal[bidx * 3 + lane];
        }
    }
}

extern "C" void kernel_launch(void* const* d_in, const int* in_sizes, int n_in,
                              void* d_out, int out_size, void* d_ws, size_t ws_size,
                              hipStream_t stream)
{
    const float* img = (const float*)d_in[0];   // [H*W, 256] f32
    const float* pal = (const float*)d_in[1];   // [256, 3]   f32
    float* out = (float*)d_out;                 // [H*W, 3]   f32

    const int npix = in_sizes[0] / 256;         // 1024*1024

    // 8192 waves = full residency on 256 CUs; grid-stride ~128 pixels/wave.
    const int threads = 256;
    const int blocks  = 2048;
    pixelart_argmax_kernel<<<blocks, threads, 0, stream>>>(img, pal, out, npix);
}